// Round 15
// baseline (63.926 us; speedup 1.0000x reference)
//
#include <hip/hip_runtime.h>
#include <hip/hip_bf16.h>

#define NB   2
#define NH   16
#define NHKV 4
#define GQ   4
#define SQL  2048
#define SKV  2048
#define DH   64
#define QBLK 32
#define KVBLK 64
#define LDK  72   // padded leading dim (bf16): 144B stride

#define QSCALE (0.125f * 1.44269504f)   // 1/sqrt(D) * log2(e)
#define M2REF  (4.0f * 1.44269504f)     // fixed softmax reference (log2 domain)

typedef __bf16 v8bf  __attribute__((ext_vector_type(8)));
typedef __bf16 v2bf  __attribute__((ext_vector_type(2)));
typedef float  f32x4 __attribute__((ext_vector_type(4)));
typedef unsigned u32x4 __attribute__((ext_vector_type(4)));

__global__ __launch_bounds__(256, 3)
void gqa_seg_attn(const float* __restrict__ q,
                  const float* __restrict__ k,
                  const float* __restrict__ v,
                  const int* __restrict__ qseg,
                  const int* __restrict__ kvseg,
                  float* __restrict__ out)
{
    __shared__ __bf16 k_lds[2][KVBLK][LDK];   // double-buffered [kv][d], shared by 4 heads
    __shared__ __bf16 vT_lds[2][DH][LDK];     // double-buffered [d][kv]
    __shared__ int    kv_start[9];            // segment boundary table

    const int tid  = threadIdx.x;
    const int lane = tid & 63;
    const int w    = tid >> 6;
    const int qt   = blockIdx.x;
    const int kvh  = blockIdx.y;
    const int b    = blockIdx.z;
    const int h    = kvh * GQ + w;            // wave w owns one head of the group
    const int q0   = qt * QBLK;

    const float* qptr   = q + (((size_t)b * NH   + h  ) * SQL) * DH;
    const float* kptr   = k + (((size_t)b * NHKV + kvh) * SKV) * DH;
    const float* vptr   = v + (((size_t)b * NHKV + kvh) * SKV) * DH;
    const int*   qsegb  = qseg  + (size_t)b * SQL;
    const int*   kvsegb = kvseg + (size_t)b * SKV;

    const int l15 = lane & 15;
    const int lg  = lane >> 4;
    const int d_a = lg * 8;

    // ---- segment boundary table: kv_start[s] = first i with kvseg[i] >= s
    if (tid < 9) kv_start[tid] = SKV;
    __syncthreads();
    {
        const int i0 = tid * 8;
        int prev = (tid == 0) ? -1 : kvsegb[i0 - 1];
        int4 va0 = *(const int4*)(kvsegb + i0);
        int4 va1 = *(const int4*)(kvsegb + i0 + 4);
        int vals[8] = {va0.x, va0.y, va0.z, va0.w, va1.x, va1.y, va1.z, va1.w};
        #pragma unroll
        for (int j = 0; j < 8; ++j) {
            int vv = vals[j];
            if (vv > prev)
                for (int s = prev + 1; s <= vv && s < 9; ++s) kv_start[s] = i0 + j;
            prev = vv;
        }
    }

    // ---- Q fragments: 2 q-subtiles x 2 d-chunks, prescaled (log2e folded)
    v8bf qfrag[2][2];
    #pragma unroll
    for (int qs = 0; qs < 2; ++qs)
        #pragma unroll
        for (int c = 0; c < 2; ++c) {
            const float* src = qptr + (size_t)(q0 + qs * 16 + l15) * DH + c * 32 + d_a;
            float4 f0 = *(const float4*)(src);
            float4 f1 = *(const float4*)(src + 4);
            v8bf t;
            t[0] = (__bf16)(f0.x * QSCALE); t[1] = (__bf16)(f0.y * QSCALE);
            t[2] = (__bf16)(f0.z * QSCALE); t[3] = (__bf16)(f0.w * QSCALE);
            t[4] = (__bf16)(f1.x * QSCALE); t[5] = (__bf16)(f1.y * QSCALE);
            t[6] = (__bf16)(f1.z * QSCALE); t[7] = (__bf16)(f1.w * QSCALE);
            qfrag[qs][c] = t;
        }

    __syncthreads();   // table ready

    // ---- per-lane valid kv range for rows q0+qs*16+l15 (same for all heads)
    int Aq[2], Bq[2];
    #pragma unroll
    for (int qs = 0; qs < 2; ++qs) {
        const int qsg = qsegb[q0 + qs * 16 + l15];
        Aq[qs] = kv_start[qsg];
        Bq[qs] = kv_start[qsg + 1];
    }

    // block tile bounds (identical for all 4 waves)
    const int smin = qsegb[q0];
    const int smax = qsegb[q0 + QBLK - 1];
    const int lo = kv_start[smin];
    const int hi = kv_start[smax + 1];
    int t0i = lo >> 6;
    int t1i = (hi + KVBLK - 1) >> 6;
    if (hi <= lo) t1i = t0i;
    const int nt = t1i - t0i;

    // staging roles
    const int krow = tid >> 2, kc0 = (tid & 3) * 16;   // K: 16 floats/thread
    const int kp   = tid & 31, vd0 = (tid >> 5) * 8;   // V: kv pair x 8 d-rows
    const int src0 = ((lg & 1) << 5) | l15;            // P redistribution sources
    const int src1 = src0 + 16;
    const bool hi2 = (lg >= 2);

    float4 ka[4], va[4];

    auto issue = [&](int kt) {
        const int kv0 = kt * KVBLK;
        const float* ks = kptr + (size_t)(kv0 + krow) * DH + kc0;
        for (int i2 = 0; i2 < 4; ++i2) ka[i2] = *(const float4*)(ks + 4 * i2);
        const float* vs0 = vptr + (size_t)(kv0 + 2 * kp) * DH + vd0;
        const float* vs1 = vs0 + DH;
        va[0] = *(const float4*)(vs0);
        va[1] = *(const float4*)(vs0 + 4);
        va[2] = *(const float4*)(vs1);
        va[3] = *(const float4*)(vs1 + 4);
    };
    auto commit = [&](int p) {
        v8bf ta, tb2;
        ta[0] = (__bf16)ka[0].x; ta[1] = (__bf16)ka[0].y;
        ta[2] = (__bf16)ka[0].z; ta[3] = (__bf16)ka[0].w;
        ta[4] = (__bf16)ka[1].x; ta[5] = (__bf16)ka[1].y;
        ta[6] = (__bf16)ka[1].z; ta[7] = (__bf16)ka[1].w;
        tb2[0] = (__bf16)ka[2].x; tb2[1] = (__bf16)ka[2].y;
        tb2[2] = (__bf16)ka[2].z; tb2[3] = (__bf16)ka[2].w;
        tb2[4] = (__bf16)ka[3].x; tb2[5] = (__bf16)ka[3].y;
        tb2[6] = (__bf16)ka[3].z; tb2[7] = (__bf16)ka[3].w;
        *(v8bf*)&k_lds[p][krow][kc0]     = ta;
        *(v8bf*)&k_lds[p][krow][kc0 + 8] = tb2;
        v2bf t;
        t[0] = (__bf16)va[0].x; t[1] = (__bf16)va[2].x; *(v2bf*)&vT_lds[p][vd0+0][2*kp] = t;
        t[0] = (__bf16)va[0].y; t[1] = (__bf16)va[2].y; *(v2bf*)&vT_lds[p][vd0+1][2*kp] = t;
        t[0] = (__bf16)va[0].z; t[1] = (__bf16)va[2].z; *(v2bf*)&vT_lds[p][vd0+2][2*kp] = t;
        t[0] = (__bf16)va[0].w; t[1] = (__bf16)va[2].w; *(v2bf*)&vT_lds[p][vd0+3][2*kp] = t;
        t[0] = (__bf16)va[1].x; t[1] = (__bf16)va[3].x; *(v2bf*)&vT_lds[p][vd0+4][2*kp] = t;
        t[0] = (__bf16)va[1].y; t[1] = (__bf16)va[3].y; *(v2bf*)&vT_lds[p][vd0+5][2*kp] = t;
        t[0] = (__bf16)va[1].z; t[1] = (__bf16)va[3].z; *(v2bf*)&vT_lds[p][vd0+6][2*kp] = t;
        t[0] = (__bf16)va[1].w; t[1] = (__bf16)va[3].w; *(v2bf*)&vT_lds[p][vd0+7][2*kp] = t;
    };

    float l_acc[2] = {0.f, 0.f};   // partial row-sum for q = qs*16 + l15
    f32x4 o_acc[2][4];
    #pragma unroll
    for (int qs = 0; qs < 2; ++qs)
        #pragma unroll
        for (int t = 0; t < 4; ++t) o_acc[qs][t] = (f32x4){0.f, 0.f, 0.f, 0.f};

    if (nt > 0) { issue(t0i); commit(0); }

    for (int i = 0; i < nt; ++i) {
        __syncthreads();                 // buf[i&1] ready for all waves
        const int p = i & 1;
        const int kv0 = (t0i + i) * KVBLK;
        if (i + 1 < nt) issue(t0i + i + 1);   // hide global latency under compute

        #pragma unroll
        for (int qs = 0; qs < 2; ++qs) {
            // ---- QK^T swapped: D = K·Q^T -> lane holds S[kv=16n+4lg+r][q=l15]
            f32x4 s[4];
            __builtin_amdgcn_s_setprio(1);
            #pragma unroll
            for (int n = 0; n < 4; ++n) {
                s[n] = (f32x4){-M2REF, -M2REF, -M2REF, -M2REF};
                #pragma unroll
                for (int c = 0; c < 2; ++c) {
                    v8bf kb = *(const v8bf*)&k_lds[p][n * 16 + l15][c * 32 + d_a];
                    s[n] = __builtin_amdgcn_mfma_f32_16x16x32_bf16(kb, qfrag[qs][c], s[n], 0, 0, 0);
                }
            }
            __builtin_amdgcn_s_setprio(0);

            // ---- mask (range compare) + exp2 + pack to bf16 pairs
            unsigned dw[4][2];
            const int kvb = kv0 + 4 * lg;
            #pragma unroll
            for (int n = 0; n < 4; ++n) {
                float pv[4];
                #pragma unroll
                for (int r = 0; r < 4; ++r) {
                    const int kv = kvb + 16 * n + r;
                    float e = __builtin_amdgcn_exp2f(s[n][r]);
                    pv[r] = (kv >= Aq[qs] && kv < Bq[qs]) ? e : 0.f;
                    l_acc[qs] += pv[r];
                }
                v2bf pk0, pk1;
                pk0[0] = (__bf16)pv[0]; pk0[1] = (__bf16)pv[1];
                pk1[0] = (__bf16)pv[2]; pk1[1] = (__bf16)pv[3];
                dw[n][0] = __builtin_bit_cast(unsigned, pk0);
                dw[n][1] = __builtin_bit_cast(unsigned, pk1);
            }

            // ---- redistribute P into PV A-fragments (shuffle + select)
            v8bf pa[2];
            #pragma unroll
            for (int c = 0; c < 2; ++c) {
                unsigned a0 = __shfl(dw[2*c][0],   src0), b0 = __shfl(dw[2*c+1][0], src0);
                unsigned a1 = __shfl(dw[2*c][1],   src0), b1 = __shfl(dw[2*c+1][1], src0);
                unsigned a2 = __shfl(dw[2*c][0],   src1), b2 = __shfl(dw[2*c+1][0], src1);
                unsigned a3 = __shfl(dw[2*c][1],   src1), b3 = __shfl(dw[2*c+1][1], src1);
                u32x4 x;
                x[0] = hi2 ? b0 : a0; x[1] = hi2 ? b1 : a1;
                x[2] = hi2 ? b2 : a2; x[3] = hi2 ? b3 : a3;
                pa[c] = __builtin_bit_cast(v8bf, x);
            }

            // ---- PV: O[q][d] += P[q][kv] V[kv][d]
            __builtin_amdgcn_s_setprio(1);
            #pragma unroll
            for (int t = 0; t < 4; ++t)
                #pragma unroll
                for (int c = 0; c < 2; ++c) {
                    v8bf vb = *(const v8bf*)&vT_lds[p][t * 16 + l15][c * 32 + d_a];
                    o_acc[qs][t] = __builtin_amdgcn_mfma_f32_16x16x32_bf16(pa[c], vb, o_acc[qs][t], 0, 0, 0);
                }
            __builtin_amdgcn_s_setprio(0);
        }

        if (i + 1 < nt) commit((i + 1) & 1);  // vmcnt wait lands after compute
    }

    // ---- epilogue: per qs, l total for q=l15 = sum over the 4 lane groups
    float* outp = out + (((size_t)b * NH + h) * SQL) * DH;
    #pragma unroll
    for (int qs = 0; qs < 2; ++qs) {
        float x = l_acc[qs];
        x += __shfl_xor(x, 16);
        x += __shfl_xor(x, 32);
        const float inv = (x > 0.f) ? (1.f / x) : 0.f;
        const int qrow_c0 = q0 + qs * 16 + (lg << 2);
        #pragma unroll
        for (int r = 0; r < 4; ++r) {
            const float invr = __shfl(inv, 4 * lg + r);
            #pragma unroll
            for (int t = 0; t < 4; ++t)
                outp[(size_t)(qrow_c0 + r) * DH + t * 16 + l15] = o_acc[qs][t][r] * invr;
        }
    }
}

extern "C" void kernel_launch(void* const* d_in, const int* in_sizes, int n_in,
                              void* d_out, int out_size, void* d_ws, size_t ws_size,
                              hipStream_t stream) {
    const float* q     = (const float*)d_in[0];
    const float* k     = (const float*)d_in[1];
    const float* v     = (const float*)d_in[2];
    const int*   qseg  = (const int*)d_in[3];
    const int*   kvseg = (const int*)d_in[4];
    float* out = (float*)d_out;

    dim3 grid(SQL / QBLK, NHKV, NB);
    dim3 block(256);
    gqa_seg_attn<<<grid, block, 0, stream>>>(q, k, v, qseg, kvseg, out);
}

// Round 16
// 38.057 us; speedup vs baseline: 1.6798x; 1.6798x over previous
//
#include <hip/hip_runtime.h>
#include <hip/hip_bf16.h>

#define NB   2
#define NH   16
#define NHKV 4
#define GQ   4
#define SQL  2048
#define SKV  2048
#define DH   64
#define QBLK 64
#define KVBLK 64
#define LDK  72   // padded leading dim (bf16): 144B stride

#define QSCALE (0.125f * 1.44269504f)   // 1/sqrt(D) * log2(e)
#define M2REF  (4.0f * 1.44269504f)     // fixed softmax reference (log2 domain)

typedef __bf16 v8bf  __attribute__((ext_vector_type(8)));
typedef __bf16 v2bf  __attribute__((ext_vector_type(2)));
typedef float  f32x4 __attribute__((ext_vector_type(4)));
typedef unsigned u32x4 __attribute__((ext_vector_type(4)));

__global__ __launch_bounds__(256, 4)
void gqa_seg_attn(const float* __restrict__ q,
                  const float* __restrict__ k,
                  const float* __restrict__ v,
                  const int* __restrict__ qseg,
                  const int* __restrict__ kvseg,
                  float* __restrict__ out)
{
    __shared__ __bf16 k_lds[2][KVBLK][LDK];   // double-buffered [kv][d]
    __shared__ __bf16 vT_lds[2][DH][LDK];     // double-buffered [d][kv]
    __shared__ int    kv_start[9];            // segment boundary table

    const int tid  = threadIdx.x;
    const int lane = tid & 63;
    const int w    = tid >> 6;
    // work-decorrelation swizzle: nt varies smoothly with qt; interleaving qt
    // across dispatch order evens per-CU work totals. Bijection (11 coprime 32).
    const int qt   = ((int)blockIdx.x * 11) & 31;
    const int h    = blockIdx.y;
    const int b    = blockIdx.z;
    const int kvh  = h / GQ;
    const int q0   = qt * QBLK;

    const float* qptr   = q + (((size_t)b * NH   + h  ) * SQL) * DH;
    const float* kptr   = k + (((size_t)b * NHKV + kvh) * SKV) * DH;
    const float* vptr   = v + (((size_t)b * NHKV + kvh) * SKV) * DH;
    const int*   qsegb  = qseg  + (size_t)b * SQL;
    const int*   kvsegb = kvseg + (size_t)b * SKV;

    const int l15 = lane & 15;
    const int lg  = lane >> 4;
    const int d_a = lg * 8;

    // ---- build segment boundary table: kv_start[s] = first i with kvseg[i] >= s
    if (tid < 9) kv_start[tid] = SKV;
    __syncthreads();
    {
        const int i0 = tid * 8;
        int prev = (tid == 0) ? -1 : kvsegb[i0 - 1];
        int4 va0 = *(const int4*)(kvsegb + i0);
        int4 va1 = *(const int4*)(kvsegb + i0 + 4);
        int vals[8] = {va0.x, va0.y, va0.z, va0.w, va1.x, va1.y, va1.z, va1.w};
        #pragma unroll
        for (int j = 0; j < 8; ++j) {
            int vv = vals[j];
            if (vv > prev)
                for (int s = prev + 1; s <= vv && s < 9; ++s) kv_start[s] = i0 + j;
            prev = vv;
        }
    }

    // ---- Q fragments: lane's q row = q0 + w*16 + l15, prescaled (log2e folded)
    v8bf qfrag[2];
    {
        const int qrow = q0 + w * 16 + l15;
        for (int c = 0; c < 2; ++c) {
            const float* src = qptr + (size_t)qrow * DH + c * 32 + d_a;
            float4 f0 = *(const float4*)(src);
            float4 f1 = *(const float4*)(src + 4);
            v8bf t;
            t[0] = (__bf16)(f0.x * QSCALE); t[1] = (__bf16)(f0.y * QSCALE);
            t[2] = (__bf16)(f0.z * QSCALE); t[3] = (__bf16)(f0.w * QSCALE);
            t[4] = (__bf16)(f1.x * QSCALE); t[5] = (__bf16)(f1.y * QSCALE);
            t[6] = (__bf16)(f1.z * QSCALE); t[7] = (__bf16)(f1.w * QSCALE);
            qfrag[c] = t;
        }
    }

    __syncthreads();   // table ready

    // ---- per-lane valid kv range for its q row (sorted kvseg => contiguous)
    const int qsg = qsegb[q0 + w * 16 + l15];
    const int Aq  = kv_start[qsg];
    const int Bq  = kv_start[qsg + 1];

    // wave band over its 16 q rows (reduce across l15; lanes differ only by l15)
    int wlo = (Aq < Bq) ? Aq : SKV;
    int whi = (Aq < Bq) ? Bq : 0;
    for (int d = 1; d < 16; d <<= 1) {
        wlo = min(wlo, __shfl_xor(wlo, d));
        whi = max(whi, __shfl_xor(whi, d));
    }

    // block tile bounds
    const int smin = qsegb[q0];
    const int smax = qsegb[q0 + QBLK - 1];
    const int lo = kv_start[smin];
    const int hi = kv_start[smax + 1];
    int t0i = lo >> 6;
    int t1i = (hi + KVBLK - 1) >> 6;
    if (hi <= lo) t1i = t0i;
    const int nt = t1i - t0i;

    // staging roles
    const int krow = tid >> 2, kc0 = (tid & 3) * 16;   // K: 16 floats/thread
    const int kp   = tid & 31, vd0 = (tid >> 5) * 8;   // V: kv pair x 8 d-rows

    float4 ka[4], va[4];

    auto issue = [&](int kt) {
        const int kv0 = kt * KVBLK;
        const float* ks = kptr + (size_t)(kv0 + krow) * DH + kc0;
        for (int i2 = 0; i2 < 4; ++i2) ka[i2] = *(const float4*)(ks + 4 * i2);
        const float* vs0 = vptr + (size_t)(kv0 + 2 * kp) * DH + vd0;
        const float* vs1 = vs0 + DH;
        va[0] = *(const float4*)(vs0);
        va[1] = *(const float4*)(vs0 + 4);
        va[2] = *(const float4*)(vs1);
        va[3] = *(const float4*)(vs1 + 4);
    };
    auto commit = [&](int p) {
        v8bf ta, tb2;
        ta[0] = (__bf16)ka[0].x; ta[1] = (__bf16)ka[0].y;
        ta[2] = (__bf16)ka[0].z; ta[3] = (__bf16)ka[0].w;
        ta[4] = (__bf16)ka[1].x; ta[5] = (__bf16)ka[1].y;
        ta[6] = (__bf16)ka[1].z; ta[7] = (__bf16)ka[1].w;
        tb2[0] = (__bf16)ka[2].x; tb2[1] = (__bf16)ka[2].y;
        tb2[2] = (__bf16)ka[2].z; tb2[3] = (__bf16)ka[2].w;
        tb2[4] = (__bf16)ka[3].x; tb2[5] = (__bf16)ka[3].y;
        tb2[6] = (__bf16)ka[3].z; tb2[7] = (__bf16)ka[3].w;
        *(v8bf*)&k_lds[p][krow][kc0]     = ta;
        *(v8bf*)&k_lds[p][krow][kc0 + 8] = tb2;
        v2bf t;
        t[0] = (__bf16)va[0].x; t[1] = (__bf16)va[2].x; *(v2bf*)&vT_lds[p][vd0+0][2*kp] = t;
        t[0] = (__bf16)va[0].y; t[1] = (__bf16)va[2].y; *(v2bf*)&vT_lds[p][vd0+1][2*kp] = t;
        t[0] = (__bf16)va[0].z; t[1] = (__bf16)va[2].z; *(v2bf*)&vT_lds[p][vd0+2][2*kp] = t;
        t[0] = (__bf16)va[0].w; t[1] = (__bf16)va[2].w; *(v2bf*)&vT_lds[p][vd0+3][2*kp] = t;
        t[0] = (__bf16)va[1].x; t[1] = (__bf16)va[3].x; *(v2bf*)&vT_lds[p][vd0+4][2*kp] = t;
        t[0] = (__bf16)va[1].y; t[1] = (__bf16)va[3].y; *(v2bf*)&vT_lds[p][vd0+5][2*kp] = t;
        t[0] = (__bf16)va[1].z; t[1] = (__bf16)va[3].z; *(v2bf*)&vT_lds[p][vd0+6][2*kp] = t;
        t[0] = (__bf16)va[1].w; t[1] = (__bf16)va[3].w; *(v2bf*)&vT_lds[p][vd0+7][2*kp] = t;
    };

    float l_acc = 0.f;          // partial row-sum for q = l15 (this wave)
    f32x4 o_acc[4];
    for (int t = 0; t < 4; ++t) o_acc[t] = (f32x4){0.f, 0.f, 0.f, 0.f};

    // shuffle sources for P redistribution (loop-invariant)
    const int src0 = ((lg & 1) << 5) | l15;
    const int src1 = src0 + 16;
    const bool hi2 = (lg >= 2);

    if (nt > 0) { issue(t0i); commit(0); }

    for (int i = 0; i < nt; ++i) {
        __syncthreads();                 // buf[i&1] ready for all waves
        const int p = i & 1;
        const int kv0 = (t0i + i) * KVBLK;
        if (i + 1 < nt) issue(t0i + i + 1);   // hide global latency under compute

        if (!(kv0 >= whi || kv0 + KVBLK <= wlo)) {   // per-wave tile skip
            // ---- QK^T swapped: D = K·Q^T -> lane holds S[kv=16n+4lg+r][q=l15]
            f32x4 s[4];
            __builtin_amdgcn_s_setprio(1);
            #pragma unroll
            for (int n = 0; n < 4; ++n) {
                s[n] = (f32x4){-M2REF, -M2REF, -M2REF, -M2REF};
                #pragma unroll
                for (int c = 0; c < 2; ++c) {
                    v8bf kb = *(const v8bf*)&k_lds[p][n * 16 + l15][c * 32 + d_a];
                    s[n] = __builtin_amdgcn_mfma_f32_16x16x32_bf16(kb, qfrag[c], s[n], 0, 0, 0);
                }
            }
            __builtin_amdgcn_s_setprio(0);

            // ---- mask (range compare) + exp2 + pack to bf16 pairs
            unsigned dw[4][2];
            const int kvb = kv0 + 4 * lg;
            #pragma unroll
            for (int n = 0; n < 4; ++n) {
                float pv[4];
                #pragma unroll
                for (int r = 0; r < 4; ++r) {
                    const int kv = kvb + 16 * n + r;
                    float e = __builtin_amdgcn_exp2f(s[n][r]);
                    pv[r] = (kv >= Aq && kv < Bq) ? e : 0.f;
                    l_acc += pv[r];
                }
                v2bf pk0, pk1;
                pk0[0] = (__bf16)pv[0]; pk0[1] = (__bf16)pv[1];
                pk1[0] = (__bf16)pv[2]; pk1[1] = (__bf16)pv[3];
                dw[n][0] = __builtin_bit_cast(unsigned, pk0);
                dw[n][1] = __builtin_bit_cast(unsigned, pk1);
            }

            // ---- redistribute P into PV A-fragments (16 bpermute + 8 select)
            v8bf pa[2];
            #pragma unroll
            for (int c = 0; c < 2; ++c) {
                unsigned a0 = __shfl(dw[2*c][0],   src0), b0 = __shfl(dw[2*c+1][0], src0);
                unsigned a1 = __shfl(dw[2*c][1],   src0), b1 = __shfl(dw[2*c+1][1], src0);
                unsigned a2 = __shfl(dw[2*c][0],   src1), b2 = __shfl(dw[2*c+1][0], src1);
                unsigned a3 = __shfl(dw[2*c][1],   src1), b3 = __shfl(dw[2*c+1][1], src1);
                u32x4 x;
                x[0] = hi2 ? b0 : a0; x[1] = hi2 ? b1 : a1;
                x[2] = hi2 ? b2 : a2; x[3] = hi2 ? b3 : a3;
                pa[c] = __builtin_bit_cast(v8bf, x);
            }

            // ---- PV: O[q][d] += P[q][kv] V[kv][d]
            __builtin_amdgcn_s_setprio(1);
            #pragma unroll
            for (int t = 0; t < 4; ++t)
                #pragma unroll
                for (int c = 0; c < 2; ++c) {
                    v8bf vb = *(const v8bf*)&vT_lds[p][t * 16 + l15][c * 32 + d_a];
                    o_acc[t] = __builtin_amdgcn_mfma_f32_16x16x32_bf16(pa[c], vb, o_acc[t], 0, 0, 0);
                }
            __builtin_amdgcn_s_setprio(0);
        }

        if (i + 1 < nt) commit((i + 1) & 1);  // vmcnt wait lands after compute
    }

    // ---- epilogue: l total for q=l15 = sum over the 4 lane groups
    float x = l_acc;
    x += __shfl_xor(x, 16);
    x += __shfl_xor(x, 32);
    const float inv = (x > 0.f) ? (1.f / x) : 0.f;

    // o_acc rows are q = 4lg + r; fetch inv for that q from lane (group 0)
    float* outp = out + (((size_t)b * NH + h) * SQL) * DH;
    const int qrow_c0 = q0 + w * 16 + (lg << 2);
    #pragma unroll
    for (int r = 0; r < 4; ++r) {
        const float invr = __shfl(inv, 4 * lg + r);
        #pragma unroll
        for (int t = 0; t < 4; ++t)
            outp[(size_t)(qrow_c0 + r) * DH + t * 16 + l15] = o_acc[t][r] * invr;
    }
}

extern "C" void kernel_launch(void* const* d_in, const int* in_sizes, int n_in,
                              void* d_out, int out_size, void* d_ws, size_t ws_size,
                              hipStream_t stream) {
    const float* q     = (const float*)d_in[0];
    const float* k     = (const float*)d_in[1];
    const float* v     = (const float*)d_in[2];
    const int*   qseg  = (const int*)d_in[3];
    const int*   kvseg = (const int*)d_in[4];
    float* out = (float*)d_out;

    dim3 grid(SQL / QBLK, NH, NB);
    dim3 block(256);
    gqa_seg_attn<<<grid, block, 0, stream>>>(q, k, v, qseg, kvseg, out);
}

// Round 17
// 38.012 us; speedup vs baseline: 1.6817x; 1.0012x over previous
//
#include <hip/hip_runtime.h>
#include <hip/hip_bf16.h>

#define NB   2
#define NH   16
#define NHKV 4
#define GQ   4
#define SQL  2048
#define SKV  2048
#define DH   64
#define QBLK 64
#define KVBLK 64
#define LDK  72   // padded leading dim (bf16): 144B stride

#define QSCALE (0.125f * 1.44269504f)   // 1/sqrt(D) * log2(e)
#define M2REF  (4.0f * 1.44269504f)     // fixed softmax reference (log2 domain)

typedef __bf16 v8bf  __attribute__((ext_vector_type(8)));
typedef __bf16 v4bf  __attribute__((ext_vector_type(4)));
typedef short  v4ss  __attribute__((ext_vector_type(4)));
typedef float  f32x4 __attribute__((ext_vector_type(4)));

__device__ __forceinline__ f32x4 mfma16(v4bf a, v4bf b, f32x4 c) {
#if __has_builtin(__builtin_amdgcn_mfma_f32_16x16x16_bf16)
    return __builtin_amdgcn_mfma_f32_16x16x16_bf16(a, b, c, 0, 0, 0);
#else
    return __builtin_amdgcn_mfma_f32_16x16x16bf16_1k(
        __builtin_bit_cast(v4ss, a), __builtin_bit_cast(v4ss, b), c, 0, 0, 0);
#endif
}

__global__ __launch_bounds__(256, 4)
void gqa_seg_attn(const float* __restrict__ q,
                  const float* __restrict__ k,
                  const float* __restrict__ v,
                  const int* __restrict__ qseg,
                  const int* __restrict__ kvseg,
                  float* __restrict__ out)
{
    __shared__ __bf16 k_lds[2][KVBLK][LDK];   // double-buffered [kv][d]
    __shared__ __bf16 vT_lds[2][DH][LDK];     // double-buffered [d][kv]
    __shared__ int    kv_start[9];            // segment boundary table

    const int tid  = threadIdx.x;
    const int lane = tid & 63;
    const int w    = tid >> 6;
    const int qt   = blockIdx.x;
    const int h    = blockIdx.y;
    const int b    = blockIdx.z;
    const int kvh  = h / GQ;
    const int q0   = qt * QBLK;

    const float* qptr   = q + (((size_t)b * NH   + h  ) * SQL) * DH;
    const float* kptr   = k + (((size_t)b * NHKV + kvh) * SKV) * DH;
    const float* vptr   = v + (((size_t)b * NHKV + kvh) * SKV) * DH;
    const int*   qsegb  = qseg  + (size_t)b * SQL;
    const int*   kvsegb = kvseg + (size_t)b * SKV;

    const int l15 = lane & 15;
    const int lg  = lane >> 4;
    const int d_a = lg * 8;

    // ---- build segment boundary table: kv_start[s] = first i with kvseg[i] >= s
    if (tid < 9) kv_start[tid] = SKV;
    __syncthreads();
    {
        const int i0 = tid * 8;
        int prev = (tid == 0) ? -1 : kvsegb[i0 - 1];
        int4 va0 = *(const int4*)(kvsegb + i0);
        int4 va1 = *(const int4*)(kvsegb + i0 + 4);
        int vals[8] = {va0.x, va0.y, va0.z, va0.w, va1.x, va1.y, va1.z, va1.w};
        #pragma unroll
        for (int j = 0; j < 8; ++j) {
            int vv = vals[j];
            if (vv > prev)
                for (int s = prev + 1; s <= vv && s < 9; ++s) kv_start[s] = i0 + j;
            prev = vv;
        }
    }

    // ---- Q fragments: lane's q row = q0 + w*16 + l15, prescaled (log2e folded)
    v8bf qfrag[2];
    {
        const int qrow = q0 + w * 16 + l15;
        for (int c = 0; c < 2; ++c) {
            const float* src = qptr + (size_t)qrow * DH + c * 32 + d_a;
            float4 f0 = *(const float4*)(src);
            float4 f1 = *(const float4*)(src + 4);
            v8bf t;
            t[0] = (__bf16)(f0.x * QSCALE); t[1] = (__bf16)(f0.y * QSCALE);
            t[2] = (__bf16)(f0.z * QSCALE); t[3] = (__bf16)(f0.w * QSCALE);
            t[4] = (__bf16)(f1.x * QSCALE); t[5] = (__bf16)(f1.y * QSCALE);
            t[6] = (__bf16)(f1.z * QSCALE); t[7] = (__bf16)(f1.w * QSCALE);
            qfrag[c] = t;
        }
    }

    __syncthreads();   // table ready

    // ---- per-lane valid kv range for its q row (sorted kvseg => contiguous)
    const int qsg = qsegb[q0 + w * 16 + l15];
    const int Aq  = kv_start[qsg];
    const int Bq  = kv_start[qsg + 1];

    // wave band over its 16 q rows
    int wlo = (Aq < Bq) ? Aq : SKV;
    int whi = (Aq < Bq) ? Bq : 0;
    for (int d = 1; d < 16; d <<= 1) {
        wlo = min(wlo, __shfl_xor(wlo, d));
        whi = max(whi, __shfl_xor(whi, d));
    }

    // block tile bounds
    const int smin = qsegb[q0];
    const int smax = qsegb[q0 + QBLK - 1];
    const int lo = kv_start[smin];
    const int hi = kv_start[smax + 1];
    int t0i = lo >> 6;
    int t1i = (hi + KVBLK - 1) >> 6;
    if (hi <= lo) t1i = t0i;
    const int nt = t1i - t0i;

    // staging roles
    const int krow = tid >> 2, kc0 = (tid & 3) * 16;   // K: 16 floats/thread
    const int kq   = tid & 15, dg = tid >> 4;          // V: kv quad x 4 d-rows

    float4 ka[4], va[4];

    auto issue = [&](int kt) {
        const int kv0 = kt * KVBLK;
        const float* ks = kptr + (size_t)(kv0 + krow) * DH + kc0;
        for (int i2 = 0; i2 < 4; ++i2) ka[i2] = *(const float4*)(ks + 4 * i2);
        const float* vs = vptr + (size_t)(kv0 + 4 * kq) * DH + 4 * dg;
        for (int j = 0; j < 4; ++j) va[j] = *(const float4*)(vs + j * DH);
    };
    auto commit = [&](int p) {
        v8bf ta, tb2;
        ta[0] = (__bf16)ka[0].x; ta[1] = (__bf16)ka[0].y;
        ta[2] = (__bf16)ka[0].z; ta[3] = (__bf16)ka[0].w;
        ta[4] = (__bf16)ka[1].x; ta[5] = (__bf16)ka[1].y;
        ta[6] = (__bf16)ka[1].z; ta[7] = (__bf16)ka[1].w;
        tb2[0] = (__bf16)ka[2].x; tb2[1] = (__bf16)ka[2].y;
        tb2[2] = (__bf16)ka[2].z; tb2[3] = (__bf16)ka[2].w;
        tb2[4] = (__bf16)ka[3].x; tb2[5] = (__bf16)ka[3].y;
        tb2[6] = (__bf16)ka[3].z; tb2[7] = (__bf16)ka[3].w;
        *(v8bf*)&k_lds[p][krow][kc0]     = ta;
        *(v8bf*)&k_lds[p][krow][kc0 + 8] = tb2;
        #pragma unroll
        for (int i2 = 0; i2 < 4; ++i2) {
            v4bf wv;
            wv[0] = (__bf16)va[0][i2]; wv[1] = (__bf16)va[1][i2];
            wv[2] = (__bf16)va[2][i2]; wv[3] = (__bf16)va[3][i2];
            *(v4bf*)&vT_lds[p][4 * dg + i2][4 * kq] = wv;
        }
    };

    float l_acc = 0.f;          // partial row-sum for q = l15 (this wave)
    f32x4 o_acc[4];
    for (int t = 0; t < 4; ++t) o_acc[t] = (f32x4){0.f, 0.f, 0.f, 0.f};

    if (nt > 0) { issue(t0i); commit(0); }

    for (int i = 0; i < nt; ++i) {
        __syncthreads();                 // buf[i&1] ready for all waves
        const int p = i & 1;
        const int kv0 = (t0i + i) * KVBLK;
        if (i + 1 < nt) issue(t0i + i + 1);   // hide global latency under compute

        if (!(kv0 >= whi || kv0 + KVBLK <= wlo)) {   // per-wave tile skip
            // ---- QK^T swapped: D = K·Q^T -> lane holds S[kv=16n+4lg+r][q=l15]
            f32x4 s[4];
            __builtin_amdgcn_s_setprio(1);
            #pragma unroll
            for (int n = 0; n < 4; ++n) {
                s[n] = (f32x4){-M2REF, -M2REF, -M2REF, -M2REF};
                #pragma unroll
                for (int c = 0; c < 2; ++c) {
                    v8bf kb = *(const v8bf*)&k_lds[p][n * 16 + l15][c * 32 + d_a];
                    s[n] = __builtin_amdgcn_mfma_f32_16x16x32_bf16(kb, qfrag[c], s[n], 0, 0, 0);
                }
            }
            __builtin_amdgcn_s_setprio(0);

            // ---- mask (range compare) + exp2 + pack: pfrag[n] IS the PV A-frag
            // for kv-chunk n (A 16x16x16: lane holds A[row=q=l15][k=4lg+r]).
            v4bf pfrag[4];
            const int kvb = kv0 + 4 * lg;
            #pragma unroll
            for (int n = 0; n < 4; ++n) {
                #pragma unroll
                for (int r = 0; r < 4; ++r) {
                    const int kv = kvb + 16 * n + r;
                    float e = __builtin_amdgcn_exp2f(s[n][r]);
                    float pv = (kv >= Aq && kv < Bq) ? e : 0.f;
                    l_acc += pv;
                    pfrag[n][r] = (__bf16)pv;
                }
            }

            // ---- PV: O[q][d] += P[q][kv] V[kv][d], K=16 chunks (zero shuffles)
            __builtin_amdgcn_s_setprio(1);
            #pragma unroll
            for (int t = 0; t < 4; ++t) {
                v4bf vb0 = *(const v4bf*)&vT_lds[p][t * 16 + l15][0 * 16 + 4 * lg];
                v4bf vb1 = *(const v4bf*)&vT_lds[p][t * 16 + l15][1 * 16 + 4 * lg];
                v4bf vb2 = *(const v4bf*)&vT_lds[p][t * 16 + l15][2 * 16 + 4 * lg];
                v4bf vb3 = *(const v4bf*)&vT_lds[p][t * 16 + l15][3 * 16 + 4 * lg];
                o_acc[t] = mfma16(pfrag[0], vb0, o_acc[t]);
                o_acc[t] = mfma16(pfrag[1], vb1, o_acc[t]);
                o_acc[t] = mfma16(pfrag[2], vb2, o_acc[t]);
                o_acc[t] = mfma16(pfrag[3], vb3, o_acc[t]);
            }
            __builtin_amdgcn_s_setprio(0);
        }

        if (i + 1 < nt) commit((i + 1) & 1);  // vmcnt wait lands after compute
    }

    // ---- epilogue: l total for q=l15 = sum over the 4 lane groups
    float x = l_acc;
    x += __shfl_xor(x, 16);
    x += __shfl_xor(x, 32);
    const float inv = (x > 0.f) ? (1.f / x) : 0.f;

    // o_acc rows are q = 4lg + r; fetch inv for that q from lane (group 0)
    float* outp = out + (((size_t)b * NH + h) * SQL) * DH;
    const int qrow_c0 = q0 + w * 16 + (lg << 2);
    #pragma unroll
    for (int r = 0; r < 4; ++r) {
        const float invr = __shfl(inv, 4 * lg + r);
        #pragma unroll
        for (int t = 0; t < 4; ++t)
            outp[(size_t)(qrow_c0 + r) * DH + t * 16 + l15] = o_acc[t][r] * invr;
    }
}

extern "C" void kernel_launch(void* const* d_in, const int* in_sizes, int n_in,
                              void* d_out, int out_size, void* d_ws, size_t ws_size,
                              hipStream_t stream) {
    const float* q     = (const float*)d_in[0];
    const float* k     = (const float*)d_in[1];
    const float* v     = (const float*)d_in[2];
    const int*   qseg  = (const int*)d_in[3];
    const int*   kvseg = (const int*)d_in[4];
    float* out = (float*)d_out;

    dim3 grid(SQL / QBLK, NH, NB);
    dim3 block(256);
    gqa_seg_attn<<<grid, block, 0, stream>>>(q, k, v, qseg, kvseg, out);
}